// Round 13
// baseline (198.042 us; speedup 1.0000x reference)
//
#include <hip/hip_runtime.h>
#include <hip/hip_bf16.h>
#include <hip/hip_fp16.h>

#define IN_CH 128
#define OUT_CH 64
#define NB 512   // edge-chunk blocks for histo/bucket_scatter (2 blocks/CU)

typedef float nf4 __attribute__((ext_vector_type(4)));   // native vec for nontemporal builtins

// ---------------- K1: per-block 256-bucket histogram of col>>8 ----------------
__global__ void __launch_bounds__(512) histo_kernel(const int* __restrict__ col,
                                                    int* __restrict__ blkcnt,
                                                    int E, int chunk) {
    __shared__ int h[256];
    int blk = blockIdx.x, tid = threadIdx.x;
    if (tid < 256) h[tid] = 0;
    __syncthreads();
    int s = blk * chunk, e = min(s + chunk, E);
    for (int i = s + tid; i < e; i += 512)
        atomicAdd(&h[col[i] >> 8], 1);          // LDS atomic
    __syncthreads();
    if (tid < 256) blkcnt[blk * 256 + tid] = h[tid];   // coalesced
}

// ---------------- K2: per-bucket exclusive scan over NB block-counts (in place) ----------------
__global__ void __launch_bounds__(256) scanblk_kernel(int* __restrict__ blkcnt,
                                                      int* __restrict__ totals) {
    __shared__ int ps[256];
    int b = blockIdx.x, tid = threadIdx.x;
    int i0 = (2 * tid) * 256 + b, i1 = (2 * tid + 1) * 256 + b;
    int a0 = blkcnt[i0], a1 = blkcnt[i1];
    int lsum = a0 + a1;
    ps[tid] = lsum;
    __syncthreads();
    for (int d = 1; d < 256; d <<= 1) {
        int t = 0;
        if (tid >= d) t = ps[tid - d];
        __syncthreads();
        if (tid >= d) ps[tid] += t;
        __syncthreads();
    }
    int excl = ps[tid] - lsum;
    blkcnt[i0] = excl;
    blkcnt[i1] = excl + a0;
    if (tid == 255) totals[b] = excl + lsum;
}

// ---------------- K3: scatter edges into bucket-contiguous tmp ----------------
__global__ void __launch_bounds__(512) bucket_scatter_kernel(const int* __restrict__ row,
                                                             const int* __restrict__ col,
                                                             const int* __restrict__ blkcnt,
                                                             const int* __restrict__ totals,
                                                             unsigned int* __restrict__ tmp,
                                                             int E, int chunk, int nbkt) {
    __shared__ int ps[256];
    __shared__ int cur[256];
    int blk = blockIdx.x, tid = threadIdx.x;
    int v = 0;
    if (tid < 256) { v = (tid < nbkt) ? totals[tid] : 0; ps[tid] = v; }
    __syncthreads();
    for (int d = 1; d < 256; d <<= 1) {
        int t = 0;
        if (tid < 256 && tid >= d) t = ps[tid - d];
        __syncthreads();
        if (tid < 256 && tid >= d) ps[tid] += t;
        __syncthreads();
    }
    if (tid < 256) cur[tid] = (ps[tid] - v) + blkcnt[blk * 256 + tid];
    __syncthreads();
    int s = blk * chunk, e = min(s + chunk, E);
    for (int i = s + tid; i < e; i += 512) {
        int c = col[i], r = row[i];
        int p = atomicAdd(&cur[c >> 8], 1);     // LDS atomic
        tmp[p] = ((unsigned)(c & 255) << 16) | (unsigned)r;
    }
}

// ---------------- K4: per-bucket 512-bin counting sort -> off/mid/dis/eidx ----------------
// Key = (target_low8 << 1) | (src >= nhalf): each node's edges become a
// lo-source run [off,mid) then hi-source run [mid,off_next) -> the hop can be
// split into two passes whose gather working set (3.2 MB z-half) fits one
// XCD's 4 MiB L2.
__global__ void __launch_bounds__(512) bucket_sort_kernel(const unsigned int* __restrict__ tmp,
                                                          const int* __restrict__ totals,
                                                          int* __restrict__ off,
                                                          int* __restrict__ mid,
                                                          float* __restrict__ dis,
                                                          unsigned short* __restrict__ eidx,
                                                          int nbkt, int E, int n, int nhalf) {
    __shared__ int bs[256];
    __shared__ int cntl[512];
    __shared__ int sc[512];
    __shared__ int posl[512];
    int b = blockIdx.x, tid = threadIdx.x;
    int v = 0;
    if (tid < 256) { v = (tid < nbkt) ? totals[tid] : 0; bs[tid] = v; }
    __syncthreads();
    for (int d = 1; d < 256; d <<= 1) {
        int t = 0;
        if (tid < 256 && tid >= d) t = bs[tid - d];
        __syncthreads();
        if (tid < 256 && tid >= d) bs[tid] += t;
        __syncthreads();
    }
    if (tid < 256) bs[tid] -= v;                 // exclusive bucket bases
    cntl[tid] = 0;
    __syncthreads();
    int s = bs[b];
    int e = s + ((b < nbkt) ? totals[b] : 0);
    for (int i = s + tid; i < e; i += 512) {
        unsigned int w = tmp[i];
        int key = ((w >> 16) << 1) | (((int)(w & 0xFFFFu) >= nhalf) ? 1 : 0);
        atomicAdd(&cntl[key], 1);                // LDS atomic
    }
    __syncthreads();
    int c = cntl[tid];
    sc[tid] = c;
    __syncthreads();
    for (int d = 1; d < 512; d <<= 1) {
        int t = 0;
        if (tid >= d) t = sc[tid - d];
        __syncthreads();
        if (tid >= d) sc[tid] += t;
        __syncthreads();
    }
    posl[tid] = s + (sc[tid] - c);               // absolute running cursor per bin
    __syncthreads();
    if (tid < 256) {
        int gid = (b << 8) + tid;
        if (gid < n) {
            int cl = cntl[2 * tid], ch = cntl[2 * tid + 1];
            off[gid] = s + (sc[2 * tid] - cl);
            mid[gid] = s + (sc[2 * tid + 1] - ch);
            dis[gid] = rsqrtf((float)(cl + ch + 1));   // +1 self-loop (gcn_norm)
        }
    }
    if (b == 0 && tid == 0) off[n] = E;
    __syncthreads();
    for (int i = s + tid; i < e; i += 512) {
        unsigned int w = tmp[i];
        int key = ((w >> 16) << 1) | (((int)(w & 0xFFFFu) >= nhalf) ? 1 : 0);
        int p = atomicAdd(&posl[key], 1);
        eidx[p] = (unsigned short)(w & 0xFFFFu);
    }
}

// ---------------- z = fp16( dis * (X @ W^T) ) : register-tiled LDS GEMM ----------------
__global__ void __launch_bounds__(256, 2) gemm_kernel(const float* __restrict__ x,
                                                      const float* __restrict__ W,
                                                      const float* __restrict__ dis,
                                                      __half* __restrict__ z, int n) {
    __shared__ float Xs[64 * 132];
    __shared__ float Ws[64 * 132];
    int t = threadIdx.x;
    int m0 = blockIdx.x * 64;
#pragma unroll
    for (int r = 0; r < 8; ++r) {               // stage W: 64x128 = 2048 float4
        int f = t + 256 * r;
        int o = f >> 5, kq = f & 31;
        float4 w = ((const float4*)W)[f];
        *(float4*)&Ws[o * 132 + kq * 4] = w;
    }
#pragma unroll
    for (int r = 0; r < 8; ++r) {               // stage X tile (clamped tail)
        int f = t + 256 * r;
        int node = f >> 5, kq = f & 31;
        int gv = min(m0 + node, n - 1);
        float4 xv = ((const float4*)(x + (size_t)gv * IN_CH))[kq];
        *(float4*)&Xs[node * 132 + kq * 4] = xv;
    }
    __syncthreads();
    int tx = t & 15, ty = t >> 4;
    float acc[4][4];
#pragma unroll
    for (int i = 0; i < 4; ++i)
#pragma unroll
        for (int j = 0; j < 4; ++j) acc[i][j] = 0.f;

#pragma unroll 4
    for (int kq = 0; kq < 32; ++kq) {
        float4 xa[4], wb[4];
#pragma unroll
        for (int i = 0; i < 4; ++i) xa[i] = *(const float4*)&Xs[(tx + 16 * i) * 132 + kq * 4];
#pragma unroll
        for (int j = 0; j < 4; ++j) wb[j] = *(const float4*)&Ws[(ty * 4 + j) * 132 + kq * 4];
#pragma unroll
        for (int i = 0; i < 4; ++i)
#pragma unroll
            for (int j = 0; j < 4; ++j) {
                float s = acc[i][j];
                s = fmaf(xa[i].x, wb[j].x, s);
                s = fmaf(xa[i].y, wb[j].y, s);
                s = fmaf(xa[i].z, wb[j].z, s);
                s = fmaf(xa[i].w, wb[j].w, s);
                acc[i][j] = s;
            }
    }
#pragma unroll
    for (int i = 0; i < 4; ++i) {
        int v = m0 + tx + 16 * i;
        if (v < n) {
            float dv = dis[v];
            union { __half2 h[2]; float2 f; } u;
            u.h[0] = __floats2half2_rn(dv * acc[i][0], dv * acc[i][1]);
            u.h[1] = __floats2half2_rn(dv * acc[i][2], dv * acc[i][3]);
            *(float2*)&z[(size_t)v * OUT_CH + ty * 4] = u.f;   // 8B aligned
        }
    }
}

// ---------------- hop pass A: lo-source gathers (+self-loop for lo nodes) -> fp32 partial ----------------
// Gather working set = zin rows [0, nhalf) = 3.2 MB -> L2-resident per XCD.
// Partial written with non-temporal stores (read-once, don't pollute L2).
__global__ void __launch_bounds__(256) hopA_kernel(const __half* __restrict__ zin,
                                                   float* __restrict__ partial,
                                                   const unsigned short* __restrict__ eidx,
                                                   const int* __restrict__ off,
                                                   const int* __restrict__ mid,
                                                   int n, int nhalf) {
    int v = (int)((blockIdx.x * 256 + threadIdx.x) >> 6);
    if (v >= n) return;
    int lane = threadIdx.x & 63;
    int grp = lane >> 3;       // edge slot in the octet
    int sub = lane & 7;        // 16B chunk of the 128B row
    int s = off[v], m = mid[v];
    float a0 = 0.f, a1 = 0.f, a2 = 0.f, a3 = 0.f;
    float a4 = 0.f, a5 = 0.f, a6 = 0.f, a7 = 0.f;
    if (grp == 0 && v < nhalf) {   // self-loop if v's row is in the lo half
        float4 raw = ((const float4*)(zin + (size_t)v * OUT_CH))[sub];
        const __half2* h2 = (const __half2*)&raw;
        float2 f0 = __half22float2(h2[0]), f1 = __half22float2(h2[1]);
        float2 f2 = __half22float2(h2[2]), f3 = __half22float2(h2[3]);
        a0 = f0.x; a1 = f0.y; a2 = f1.x; a3 = f1.y;
        a4 = f2.x; a5 = f2.y; a6 = f3.x; a7 = f3.y;
    }
    int i = s + grp;
    bool have = (i < m);
    int r = have ? (int)eidx[i] : 0;
    while (have) {
        int j = i + 8;
        bool hnext = (j < m);
        int rn = hnext ? (int)eidx[j] : 0;
        float4 raw = ((const float4*)(zin + (size_t)r * OUT_CH))[sub];
        const __half2* h2 = (const __half2*)&raw;
        float2 f0 = __half22float2(h2[0]), f1 = __half22float2(h2[1]);
        float2 f2 = __half22float2(h2[2]), f3 = __half22float2(h2[3]);
        a0 += f0.x; a1 += f0.y; a2 += f1.x; a3 += f1.y;
        a4 += f2.x; a5 += f2.y; a6 += f3.x; a7 += f3.y;
        r = rn; i = j; have = hnext;
    }
#pragma unroll
    for (int mm = 8; mm <= 32; mm <<= 1) {
        a0 += __shfl_xor(a0, mm, 64); a1 += __shfl_xor(a1, mm, 64);
        a2 += __shfl_xor(a2, mm, 64); a3 += __shfl_xor(a3, mm, 64);
        a4 += __shfl_xor(a4, mm, 64); a5 += __shfl_xor(a5, mm, 64);
        a6 += __shfl_xor(a6, mm, 64); a7 += __shfl_xor(a7, mm, 64);
    }
    if (grp == 0) {
        float* pp = partial + (size_t)v * OUT_CH + sub * 8;
        nf4 s0 = {a0, a1, a2, a3};
        nf4 s1 = {a4, a5, a6, a7};
        __builtin_nontemporal_store(s0, (nf4*)pp);
        __builtin_nontemporal_store(s1, (nf4*)(pp + 4));
    }
}

// ---------------- hop pass B: hi-source gathers (+self for hi nodes) + partial -> final ----------------
// MODE 0: out(half) = dis^2 * t (next z);  MODE 1: out(float) = dis * t + bias.
template <int MODE>
__global__ void __launch_bounds__(256) hopB_kernel(const __half* __restrict__ zin,
                                                   const float* __restrict__ partial,
                                                   void* __restrict__ out,
                                                   const unsigned short* __restrict__ eidx,
                                                   const int* __restrict__ off,
                                                   const int* __restrict__ mid,
                                                   const float* __restrict__ dis,
                                                   const float* __restrict__ bias,
                                                   int n, int nhalf) {
    int v = (int)((blockIdx.x * 256 + threadIdx.x) >> 6);
    if (v >= n) return;
    int lane = threadIdx.x & 63;
    int grp = lane >> 3;
    int sub = lane & 7;
    int m = mid[v], e = off[v + 1];
    float a0 = 0.f, a1 = 0.f, a2 = 0.f, a3 = 0.f;
    float a4 = 0.f, a5 = 0.f, a6 = 0.f, a7 = 0.f;
    if (grp == 0) {
        const float* pp = partial + (size_t)v * OUT_CH + sub * 8;
        nf4 p0 = __builtin_nontemporal_load((const nf4*)pp);
        nf4 p1 = __builtin_nontemporal_load((const nf4*)(pp + 4));
        a0 = p0.x; a1 = p0.y; a2 = p0.z; a3 = p0.w;
        a4 = p1.x; a5 = p1.y; a6 = p1.z; a7 = p1.w;
        if (v >= nhalf) {   // self-loop if v's row is in the hi half
            float4 raw = ((const float4*)(zin + (size_t)v * OUT_CH))[sub];
            const __half2* h2 = (const __half2*)&raw;
            float2 f0 = __half22float2(h2[0]), f1 = __half22float2(h2[1]);
            float2 f2 = __half22float2(h2[2]), f3 = __half22float2(h2[3]);
            a0 += f0.x; a1 += f0.y; a2 += f1.x; a3 += f1.y;
            a4 += f2.x; a5 += f2.y; a6 += f3.x; a7 += f3.y;
        }
    }
    int i = m + grp;
    bool have = (i < e);
    int r = have ? (int)eidx[i] : 0;
    while (have) {
        int j = i + 8;
        bool hnext = (j < e);
        int rn = hnext ? (int)eidx[j] : 0;
        float4 raw = ((const float4*)(zin + (size_t)r * OUT_CH))[sub];
        const __half2* h2 = (const __half2*)&raw;
        float2 f0 = __half22float2(h2[0]), f1 = __half22float2(h2[1]);
        float2 f2 = __half22float2(h2[2]), f3 = __half22float2(h2[3]);
        a0 += f0.x; a1 += f0.y; a2 += f1.x; a3 += f1.y;
        a4 += f2.x; a5 += f2.y; a6 += f3.x; a7 += f3.y;
        r = rn; i = j; have = hnext;
    }
#pragma unroll
    for (int mm = 8; mm <= 32; mm <<= 1) {
        a0 += __shfl_xor(a0, mm, 64); a1 += __shfl_xor(a1, mm, 64);
        a2 += __shfl_xor(a2, mm, 64); a3 += __shfl_xor(a3, mm, 64);
        a4 += __shfl_xor(a4, mm, 64); a5 += __shfl_xor(a5, mm, 64);
        a6 += __shfl_xor(a6, mm, 64); a7 += __shfl_xor(a7, mm, 64);
    }
    if (grp == 0) {
        float dv = dis[v];
        if (MODE == 0) {
            float sc = dv * dv;
            union { __half2 h[4]; float4 f; } u;
            u.h[0] = __floats2half2_rn(sc * a0, sc * a1);
            u.h[1] = __floats2half2_rn(sc * a2, sc * a3);
            u.h[2] = __floats2half2_rn(sc * a4, sc * a5);
            u.h[3] = __floats2half2_rn(sc * a6, sc * a7);
            ((float4*)((__half*)out + (size_t)v * OUT_CH))[sub] = u.f;
        } else {
            const float4* bp = (const float4*)(bias + sub * 8);
            float4 b0 = bp[0], b1 = bp[1];
            float* op = (float*)out + (size_t)v * OUT_CH + sub * 8;
            nf4 s0 = {fmaf(dv, a0, b0.x), fmaf(dv, a1, b0.y),
                      fmaf(dv, a2, b0.z), fmaf(dv, a3, b0.w)};
            nf4 s1 = {fmaf(dv, a4, b1.x), fmaf(dv, a5, b1.y),
                      fmaf(dv, a6, b1.z), fmaf(dv, a7, b1.w)};
            __builtin_nontemporal_store(s0, (nf4*)op);
            __builtin_nontemporal_store(s1, (nf4*)(op + 4));
        }
    }
}

extern "C" void kernel_launch(void* const* d_in, const int* in_sizes, int n_in,
                              void* d_out, int out_size, void* d_ws, size_t ws_size,
                              hipStream_t stream) {
    const float* x = (const float*)d_in[0];
    const int* ei = (const int*)d_in[1];
    const float* W = (const float*)d_in[2];
    const float* b = (const float*)d_in[3];
    int n = in_sizes[0] / IN_CH;   // 50000
    int E = in_sizes[1] / 2;       // 800000
    const int* row = ei;           // edge_index[0] = source
    const int* col = ei + E;       // edge_index[1] = target
    int nhalf = n / 2;

    char* ws = (char*)d_ws;
    size_t o = 0;
    auto alloc = [&](size_t bytes) -> void* {
        void* p = ws + o;
        o += (bytes + 255) & ~(size_t)255;
        return p;
    };
    int nbkt = (n + 255) >> 8;      // 196
    int chunk = (E + NB - 1) / NB;  // 1563

    int*            blkcnt = (int*)alloc((size_t)NB * 256 * 4);
    int*            totals = (int*)alloc(256 * 4);
    unsigned int*   tmp    = (unsigned int*)alloc((size_t)E * 4);
    int*            off    = (int*)alloc((size_t)(n + 1) * 4);
    int*            midp   = (int*)alloc((size_t)n * 4);
    float*          dis    = (float*)alloc((size_t)n * 4);
    unsigned short* eidx   = (unsigned short*)alloc((size_t)E * 2);
    __half*         zA     = (__half*)alloc((size_t)n * OUT_CH * 2);
    __half*         zB     = (__half*)alloc((size_t)n * OUT_CH * 2);
    float*          part   = (float*)alloc((size_t)n * OUT_CH * 4);

    histo_kernel<<<NB, 512, 0, stream>>>(col, blkcnt, E, chunk);
    scanblk_kernel<<<nbkt, 256, 0, stream>>>(blkcnt, totals);
    bucket_scatter_kernel<<<NB, 512, 0, stream>>>(row, col, blkcnt, totals, tmp, E, chunk, nbkt);
    bucket_sort_kernel<<<nbkt, 512, 0, stream>>>(tmp, totals, off, midp, dis, eidx, nbkt, E, n, nhalf);
    gemm_kernel<<<(n + 63) / 64, 256, 0, stream>>>(x, W, dis, zA, n);
    int hopBlocks = (n + 3) / 4;   // wave per node
    hopA_kernel<<<hopBlocks, 256, 0, stream>>>(zA, part, eidx, off, midp, n, nhalf);
    hopB_kernel<0><<<hopBlocks, 256, 0, stream>>>(zA, part, zB, eidx, off, midp, dis, nullptr, n, nhalf);
    hopA_kernel<<<hopBlocks, 256, 0, stream>>>(zB, part, eidx, off, midp, n, nhalf);
    hopB_kernel<1><<<hopBlocks, 256, 0, stream>>>(zB, part, d_out, eidx, off, midp, dis, b, n, nhalf);
}

// Round 14
// 166.587 us; speedup vs baseline: 1.1888x; 1.1888x over previous
//
#include <hip/hip_runtime.h>
#include <hip/hip_bf16.h>
#include <hip/hip_fp16.h>

#define IN_CH 128
#define OUT_CH 64
#define NB 512   // edge-chunk blocks for histo/bucket_scatter (2 blocks/CU)

// ---------------- K1: per-block 256-bucket histogram of col>>8 ----------------
__global__ void __launch_bounds__(512) histo_kernel(const int* __restrict__ col,
                                                    int* __restrict__ blkcnt,
                                                    int E, int chunk) {
    __shared__ int h[256];
    int blk = blockIdx.x, tid = threadIdx.x;
    if (tid < 256) h[tid] = 0;
    __syncthreads();
    int s = blk * chunk, e = min(s + chunk, E);
    for (int i = s + tid; i < e; i += 512)
        atomicAdd(&h[col[i] >> 8], 1);          // LDS atomic
    __syncthreads();
    if (tid < 256) blkcnt[blk * 256 + tid] = h[tid];   // coalesced
}

// ---------------- K2: per-bucket exclusive scan over NB block-counts (in place) ----------------
__global__ void __launch_bounds__(256) scanblk_kernel(int* __restrict__ blkcnt,
                                                      int* __restrict__ totals) {
    __shared__ int ps[256];
    int b = blockIdx.x, tid = threadIdx.x;
    int i0 = (2 * tid) * 256 + b, i1 = (2 * tid + 1) * 256 + b;
    int a0 = blkcnt[i0], a1 = blkcnt[i1];
    int lsum = a0 + a1;
    ps[tid] = lsum;
    __syncthreads();
    for (int d = 1; d < 256; d <<= 1) {
        int t = 0;
        if (tid >= d) t = ps[tid - d];
        __syncthreads();
        if (tid >= d) ps[tid] += t;
        __syncthreads();
    }
    int excl = ps[tid] - lsum;
    blkcnt[i0] = excl;
    blkcnt[i1] = excl + a0;
    if (tid == 255) totals[b] = excl + lsum;
}

// ---------------- K3: scatter edges into bucket-contiguous tmp ----------------
__global__ void __launch_bounds__(512) bucket_scatter_kernel(const int* __restrict__ row,
                                                             const int* __restrict__ col,
                                                             const int* __restrict__ blkcnt,
                                                             const int* __restrict__ totals,
                                                             unsigned int* __restrict__ tmp,
                                                             int E, int chunk, int nbkt) {
    __shared__ int ps[256];
    __shared__ int cur[256];
    int blk = blockIdx.x, tid = threadIdx.x;
    int v = 0;
    if (tid < 256) { v = (tid < nbkt) ? totals[tid] : 0; ps[tid] = v; }
    __syncthreads();
    for (int d = 1; d < 256; d <<= 1) {
        int t = 0;
        if (tid < 256 && tid >= d) t = ps[tid - d];
        __syncthreads();
        if (tid < 256 && tid >= d) ps[tid] += t;
        __syncthreads();
    }
    if (tid < 256) cur[tid] = (ps[tid] - v) + blkcnt[blk * 256 + tid];
    __syncthreads();
    int s = blk * chunk, e = min(s + chunk, E);
    for (int i = s + tid; i < e; i += 512) {
        int c = col[i], r = row[i];
        int p = atomicAdd(&cur[c >> 8], 1);     // LDS atomic
        tmp[p] = ((unsigned)(c & 255) << 16) | (unsigned)r;
    }
}

// ---------------- K4: per-bucket counting sort -> off/dis/eidx ----------------
__global__ void __launch_bounds__(512) bucket_sort_kernel(const unsigned int* __restrict__ tmp,
                                                          const int* __restrict__ totals,
                                                          int* __restrict__ off,
                                                          float* __restrict__ dis,
                                                          unsigned short* __restrict__ eidx,
                                                          int nbkt, int E, int n) {
    __shared__ int bs[256];
    __shared__ int cntl[256];
    __shared__ int sc[256];
    __shared__ int posl[256];
    int b = blockIdx.x, tid = threadIdx.x;
    int v = 0;
    if (tid < 256) { v = (tid < nbkt) ? totals[tid] : 0; bs[tid] = v; }
    __syncthreads();
    for (int d = 1; d < 256; d <<= 1) {
        int t = 0;
        if (tid < 256 && tid >= d) t = bs[tid - d];
        __syncthreads();
        if (tid < 256 && tid >= d) bs[tid] += t;
        __syncthreads();
    }
    if (tid < 256) bs[tid] -= v;                 // exclusive bucket bases
    if (tid < 256) cntl[tid] = 0;
    __syncthreads();
    int s = bs[b];
    int e = s + ((b < nbkt) ? totals[b] : 0);
    for (int i = s + tid; i < e; i += 512)
        atomicAdd(&cntl[tmp[i] >> 16], 1);       // LDS atomic
    __syncthreads();
    int c = 0;
    if (tid < 256) { c = cntl[tid]; sc[tid] = c; }
    __syncthreads();
    for (int d = 1; d < 256; d <<= 1) {
        int t = 0;
        if (tid < 256 && tid >= d) t = sc[tid - d];
        __syncthreads();
        if (tid < 256 && tid >= d) sc[tid] += t;
        __syncthreads();
    }
    if (tid < 256) {
        int excl = sc[tid] - c;
        int gid = (b << 8) + tid;
        if (gid < n) {
            off[gid] = s + excl;
            dis[gid] = rsqrtf((float)(c + 1));   // +1 self-loop (gcn_norm)
        }
        posl[tid] = s + excl;                    // absolute running cursor
    }
    if (b == 0 && tid == 0) off[n] = E;
    __syncthreads();
    for (int i = s + tid; i < e; i += 512) {
        unsigned int w = tmp[i];
        int p = atomicAdd(&posl[w >> 16], 1);
        eidx[p] = (unsigned short)(w & 0xFFFFu);
    }
}

// ---------------- z = fp16( dis * (X @ W^T) ) : register-tiled LDS GEMM ----------------
__global__ void __launch_bounds__(256, 2) gemm_kernel(const float* __restrict__ x,
                                                      const float* __restrict__ W,
                                                      const float* __restrict__ dis,
                                                      __half* __restrict__ z, int n) {
    __shared__ float Xs[64 * 132];
    __shared__ float Ws[64 * 132];
    int t = threadIdx.x;
    int m0 = blockIdx.x * 64;
#pragma unroll
    for (int r = 0; r < 8; ++r) {               // stage W: 64x128 = 2048 float4
        int f = t + 256 * r;
        int o = f >> 5, kq = f & 31;
        float4 w = ((const float4*)W)[f];
        *(float4*)&Ws[o * 132 + kq * 4] = w;
    }
#pragma unroll
    for (int r = 0; r < 8; ++r) {               // stage X tile (clamped tail)
        int f = t + 256 * r;
        int node = f >> 5, kq = f & 31;
        int gv = min(m0 + node, n - 1);
        float4 xv = ((const float4*)(x + (size_t)gv * IN_CH))[kq];
        *(float4*)&Xs[node * 132 + kq * 4] = xv;
    }
    __syncthreads();
    int tx = t & 15, ty = t >> 4;
    float acc[4][4];
#pragma unroll
    for (int i = 0; i < 4; ++i)
#pragma unroll
        for (int j = 0; j < 4; ++j) acc[i][j] = 0.f;

#pragma unroll 4
    for (int kq = 0; kq < 32; ++kq) {
        float4 xa[4], wb[4];
#pragma unroll
        for (int i = 0; i < 4; ++i) xa[i] = *(const float4*)&Xs[(tx + 16 * i) * 132 + kq * 4];
#pragma unroll
        for (int j = 0; j < 4; ++j) wb[j] = *(const float4*)&Ws[(ty * 4 + j) * 132 + kq * 4];
#pragma unroll
        for (int i = 0; i < 4; ++i)
#pragma unroll
            for (int j = 0; j < 4; ++j) {
                float s = acc[i][j];
                s = fmaf(xa[i].x, wb[j].x, s);
                s = fmaf(xa[i].y, wb[j].y, s);
                s = fmaf(xa[i].z, wb[j].z, s);
                s = fmaf(xa[i].w, wb[j].w, s);
                acc[i][j] = s;
            }
    }
#pragma unroll
    for (int i = 0; i < 4; ++i) {
        int v = m0 + tx + 16 * i;
        if (v < n) {
            float dv = dis[v];
            union { __half2 h[2]; float2 f; } u;
            u.h[0] = __floats2half2_rn(dv * acc[i][0], dv * acc[i][1]);
            u.h[1] = __floats2half2_rn(dv * acc[i][2], dv * acc[i][3]);
            *(float2*)&z[(size_t)v * OUT_CH + ty * 4] = u.f;   // 8B aligned
        }
    }
}

// ---------------- propagation hop: wave per node, TWO 8-edge gather batches in flight ----------------
// t[v] = zin[v] + sum_{edges} zin[row]; rows are 64 halves = 128B.
// lane = grp*8+sub: grp = edge slot, sub = 16B chunk. Batch A = edges i..i+7,
// batch B = i+8..i+15 issued together (masked loads, zero-init) -> 2x MLP;
// descriptors for both prefetched one iteration ahead.
// MODE 0: out(half) = dis^2 * t (next z);  MODE 1: out(float) = dis * t + bias.
template <int MODE>
__global__ void __launch_bounds__(256) hop_kernel(const __half* __restrict__ zin,
                                                  void* __restrict__ out,
                                                  const unsigned short* __restrict__ eidx,
                                                  const int* __restrict__ off,
                                                  const float* __restrict__ dis,
                                                  const float* __restrict__ bias, int n) {
    int v = (int)((blockIdx.x * 256 + threadIdx.x) >> 6);
    if (v >= n) return;
    int lane = threadIdx.x & 63;
    int grp = lane >> 3;       // edge slot in the octet
    int sub = lane & 7;        // 16B chunk of the 128B row
    int s = off[v], e = off[v + 1];
    float a0 = 0.f, a1 = 0.f, a2 = 0.f, a3 = 0.f;
    float a4 = 0.f, a5 = 0.f, a6 = 0.f, a7 = 0.f;
    if (grp == 0) {            // self-loop term (z already carries dis scaling)
        float4 raw = ((const float4*)(zin + (size_t)v * OUT_CH))[sub];
        const __half2* h2 = (const __half2*)&raw;
        float2 f0 = __half22float2(h2[0]), f1 = __half22float2(h2[1]);
        float2 f2 = __half22float2(h2[2]), f3 = __half22float2(h2[3]);
        a0 = f0.x; a1 = f0.y; a2 = f1.x; a3 = f1.y;
        a4 = f2.x; a5 = f2.y; a6 = f3.x; a7 = f3.y;
    }
    int i0 = s + grp, i1 = s + grp + 8;
    bool h0 = i0 < e, h1 = i1 < e;
    int r0 = h0 ? (int)eidx[i0] : 0;
    int r1 = h1 ? (int)eidx[i1] : 0;
    while (h0) {               // h1 implies h0
        int j0 = i0 + 16, j1 = i1 + 16;
        bool g0 = j0 < e, g1 = j1 < e;
        int q0 = g0 ? (int)eidx[j0] : 0;    // prefetch next descriptors
        int q1 = g1 ? (int)eidx[j1] : 0;
        float4 rawA = make_float4(0.f, 0.f, 0.f, 0.f);
        float4 rawB = make_float4(0.f, 0.f, 0.f, 0.f);
        if (h0) rawA = ((const float4*)(zin + (size_t)r0 * OUT_CH))[sub];
        if (h1) rawB = ((const float4*)(zin + (size_t)r1 * OUT_CH))[sub];
        {
            const __half2* hA = (const __half2*)&rawA;
            float2 f0 = __half22float2(hA[0]), f1 = __half22float2(hA[1]);
            float2 f2 = __half22float2(hA[2]), f3 = __half22float2(hA[3]);
            a0 += f0.x; a1 += f0.y; a2 += f1.x; a3 += f1.y;
            a4 += f2.x; a5 += f2.y; a6 += f3.x; a7 += f3.y;
        }
        {
            const __half2* hB = (const __half2*)&rawB;
            float2 f0 = __half22float2(hB[0]), f1 = __half22float2(hB[1]);
            float2 f2 = __half22float2(hB[2]), f3 = __half22float2(hB[3]);
            a0 += f0.x; a1 += f0.y; a2 += f1.x; a3 += f1.y;
            a4 += f2.x; a5 += f2.y; a6 += f3.x; a7 += f3.y;
        }
        i0 = j0; i1 = j1; r0 = q0; r1 = q1; h0 = g0; h1 = g1;
    }
    // reduce the 8 edge slots (lanes differing in bits 3..5)
#pragma unroll
    for (int m = 8; m <= 32; m <<= 1) {
        a0 += __shfl_xor(a0, m, 64); a1 += __shfl_xor(a1, m, 64);
        a2 += __shfl_xor(a2, m, 64); a3 += __shfl_xor(a3, m, 64);
        a4 += __shfl_xor(a4, m, 64); a5 += __shfl_xor(a5, m, 64);
        a6 += __shfl_xor(a6, m, 64); a7 += __shfl_xor(a7, m, 64);
    }
    if (grp == 0) {
        float dv = dis[v];
        if (MODE == 0) {
            float sc = dv * dv;
            union { __half2 h[4]; float4 f; } u;
            u.h[0] = __floats2half2_rn(sc * a0, sc * a1);
            u.h[1] = __floats2half2_rn(sc * a2, sc * a3);
            u.h[2] = __floats2half2_rn(sc * a4, sc * a5);
            u.h[3] = __floats2half2_rn(sc * a6, sc * a7);
            ((float4*)((__half*)out + (size_t)v * OUT_CH))[sub] = u.f;
        } else {
            const float4* bp = (const float4*)(bias + sub * 8);
            float4 b0 = bp[0], b1 = bp[1];
            float* op = (float*)out + (size_t)v * OUT_CH + sub * 8;
            *(float4*)op = make_float4(fmaf(dv, a0, b0.x), fmaf(dv, a1, b0.y),
                                       fmaf(dv, a2, b0.z), fmaf(dv, a3, b0.w));
            *(float4*)(op + 4) = make_float4(fmaf(dv, a4, b1.x), fmaf(dv, a5, b1.y),
                                             fmaf(dv, a6, b1.z), fmaf(dv, a7, b1.w));
        }
    }
}

extern "C" void kernel_launch(void* const* d_in, const int* in_sizes, int n_in,
                              void* d_out, int out_size, void* d_ws, size_t ws_size,
                              hipStream_t stream) {
    const float* x = (const float*)d_in[0];
    const int* ei = (const int*)d_in[1];
    const float* W = (const float*)d_in[2];
    const float* b = (const float*)d_in[3];
    int n = in_sizes[0] / IN_CH;   // 50000
    int E = in_sizes[1] / 2;       // 800000
    const int* row = ei;           // edge_index[0] = source
    const int* col = ei + E;       // edge_index[1] = target

    char* ws = (char*)d_ws;
    size_t o = 0;
    auto alloc = [&](size_t bytes) -> void* {
        void* p = ws + o;
        o += (bytes + 255) & ~(size_t)255;
        return p;
    };
    int nbkt = (n + 255) >> 8;      // 196
    int chunk = (E + NB - 1) / NB;  // 1563

    int*            blkcnt = (int*)alloc((size_t)NB * 256 * 4);
    int*            totals = (int*)alloc(256 * 4);
    unsigned int*   tmp    = (unsigned int*)alloc((size_t)E * 4);
    int*            off    = (int*)alloc((size_t)(n + 1) * 4);
    float*          dis    = (float*)alloc((size_t)n * 4);
    unsigned short* eidx   = (unsigned short*)alloc((size_t)E * 2);
    __half*         zA     = (__half*)alloc((size_t)n * OUT_CH * 2);
    __half*         zB     = (__half*)alloc((size_t)n * OUT_CH * 2);

    histo_kernel<<<NB, 512, 0, stream>>>(col, blkcnt, E, chunk);
    scanblk_kernel<<<nbkt, 256, 0, stream>>>(blkcnt, totals);
    bucket_scatter_kernel<<<NB, 512, 0, stream>>>(row, col, blkcnt, totals, tmp, E, chunk, nbkt);
    bucket_sort_kernel<<<nbkt, 512, 0, stream>>>(tmp, totals, off, dis, eidx, nbkt, E, n);
    gemm_kernel<<<(n + 63) / 64, 256, 0, stream>>>(x, W, dis, zA, n);
    int hopBlocks = (n + 3) / 4;   // wave per node
    hop_kernel<0><<<hopBlocks, 256, 0, stream>>>(zA, zB, eidx, off, dis, nullptr, n);
    hop_kernel<1><<<hopBlocks, 256, 0, stream>>>(zB, d_out, eidx, off, dis, b, n);
}

// Round 15
// 159.880 us; speedup vs baseline: 1.2387x; 1.0420x over previous
//
#include <hip/hip_runtime.h>
#include <hip/hip_bf16.h>
#include <hip/hip_fp16.h>

#define IN_CH 128
#define OUT_CH 64
#define NB 512   // edge-chunk blocks for histo/bucket_scatter (2 blocks/CU)

typedef _Float16 hh2 __attribute__((ext_vector_type(2)));   // native half2 for v_dot2

// ---------------- K1: per-block 256-bucket histogram of col>>8 ----------------
__global__ void __launch_bounds__(512) histo_kernel(const int* __restrict__ col,
                                                    int* __restrict__ blkcnt,
                                                    int E, int chunk) {
    __shared__ int h[256];
    int blk = blockIdx.x, tid = threadIdx.x;
    if (tid < 256) h[tid] = 0;
    __syncthreads();
    int s = blk * chunk, e = min(s + chunk, E);
    for (int i = s + tid; i < e; i += 512)
        atomicAdd(&h[col[i] >> 8], 1);          // LDS atomic
    __syncthreads();
    if (tid < 256) blkcnt[blk * 256 + tid] = h[tid];   // coalesced
}

// ---------------- K2: per-bucket exclusive scan over NB block-counts (in place) ----------------
__global__ void __launch_bounds__(256) scanblk_kernel(int* __restrict__ blkcnt,
                                                      int* __restrict__ totals) {
    __shared__ int ps[256];
    int b = blockIdx.x, tid = threadIdx.x;
    int i0 = (2 * tid) * 256 + b, i1 = (2 * tid + 1) * 256 + b;
    int a0 = blkcnt[i0], a1 = blkcnt[i1];
    int lsum = a0 + a1;
    ps[tid] = lsum;
    __syncthreads();
    for (int d = 1; d < 256; d <<= 1) {
        int t = 0;
        if (tid >= d) t = ps[tid - d];
        __syncthreads();
        if (tid >= d) ps[tid] += t;
        __syncthreads();
    }
    int excl = ps[tid] - lsum;
    blkcnt[i0] = excl;
    blkcnt[i1] = excl + a0;
    if (tid == 255) totals[b] = excl + lsum;
}

// ---------------- K3: scatter edges into bucket-contiguous tmp ----------------
__global__ void __launch_bounds__(512) bucket_scatter_kernel(const int* __restrict__ row,
                                                             const int* __restrict__ col,
                                                             const int* __restrict__ blkcnt,
                                                             const int* __restrict__ totals,
                                                             unsigned int* __restrict__ tmp,
                                                             int E, int chunk, int nbkt) {
    __shared__ int ps[256];
    __shared__ int cur[256];
    int blk = blockIdx.x, tid = threadIdx.x;
    int v = 0;
    if (tid < 256) { v = (tid < nbkt) ? totals[tid] : 0; ps[tid] = v; }
    __syncthreads();
    for (int d = 1; d < 256; d <<= 1) {
        int t = 0;
        if (tid < 256 && tid >= d) t = ps[tid - d];
        __syncthreads();
        if (tid < 256 && tid >= d) ps[tid] += t;
        __syncthreads();
    }
    if (tid < 256) cur[tid] = (ps[tid] - v) + blkcnt[blk * 256 + tid];
    __syncthreads();
    int s = blk * chunk, e = min(s + chunk, E);
    for (int i = s + tid; i < e; i += 512) {
        int c = col[i], r = row[i];
        int p = atomicAdd(&cur[c >> 8], 1);     // LDS atomic
        tmp[p] = ((unsigned)(c & 255) << 16) | (unsigned)r;
    }
}

// ---------------- K4: per-bucket counting sort -> off/dis/eidx ----------------
__global__ void __launch_bounds__(512) bucket_sort_kernel(const unsigned int* __restrict__ tmp,
                                                          const int* __restrict__ totals,
                                                          int* __restrict__ off,
                                                          float* __restrict__ dis,
                                                          unsigned short* __restrict__ eidx,
                                                          int nbkt, int E, int n) {
    __shared__ int bs[256];
    __shared__ int cntl[256];
    __shared__ int sc[256];
    __shared__ int posl[256];
    int b = blockIdx.x, tid = threadIdx.x;
    int v = 0;
    if (tid < 256) { v = (tid < nbkt) ? totals[tid] : 0; bs[tid] = v; }
    __syncthreads();
    for (int d = 1; d < 256; d <<= 1) {
        int t = 0;
        if (tid < 256 && tid >= d) t = bs[tid - d];
        __syncthreads();
        if (tid < 256 && tid >= d) bs[tid] += t;
        __syncthreads();
    }
    if (tid < 256) bs[tid] -= v;                 // exclusive bucket bases
    if (tid < 256) cntl[tid] = 0;
    __syncthreads();
    int s = bs[b];
    int e = s + ((b < nbkt) ? totals[b] : 0);
    for (int i = s + tid; i < e; i += 512)
        atomicAdd(&cntl[tmp[i] >> 16], 1);       // LDS atomic
    __syncthreads();
    int c = 0;
    if (tid < 256) { c = cntl[tid]; sc[tid] = c; }
    __syncthreads();
    for (int d = 1; d < 256; d <<= 1) {
        int t = 0;
        if (tid < 256 && tid >= d) t = sc[tid - d];
        __syncthreads();
        if (tid < 256 && tid >= d) sc[tid] += t;
        __syncthreads();
    }
    if (tid < 256) {
        int excl = sc[tid] - c;
        int gid = (b << 8) + tid;
        if (gid < n) {
            off[gid] = s + excl;
            dis[gid] = rsqrtf((float)(c + 1));   // +1 self-loop (gcn_norm)
        }
        posl[tid] = s + excl;                    // absolute running cursor
    }
    if (b == 0 && tid == 0) off[n] = E;
    __syncthreads();
    for (int i = s + tid; i < e; i += 512) {
        unsigned int w = tmp[i];
        int p = atomicAdd(&posl[w >> 16], 1);
        eidx[p] = (unsigned short)(w & 0xFFFFu);
    }
}

// ---------------- z = fp16( dis * (X @ W^T) ) : half2 LDS + v_dot2_f32_f16 ----------------
// Xs/Ws staged as packed half2 (stride 66: b64 row reads broadcast per tx/ty,
// conflict-free). Inner loop = fdot2 (2 MAC/instr, fp32 acc): half the VALU
// and half the LDS bytes of the fp32 version; 33.8 KB LDS -> 4 blocks/CU.
__global__ void __launch_bounds__(256) gemm_kernel(const float* __restrict__ x,
                                                   const float* __restrict__ W,
                                                   const float* __restrict__ dis,
                                                   __half* __restrict__ z, int n) {
    __shared__ hh2 Xs[64 * 66];
    __shared__ hh2 Ws[64 * 66];
    int t = threadIdx.x;
    int m0 = blockIdx.x * 64;
#pragma unroll
    for (int r = 0; r < 8; ++r) {               // stage W: 64x128 fp32 -> half2
        int f = t + 256 * r;                    // float4 index; row=f>>5, kq=f&31
        int o = f >> 5, kq = f & 31;
        float4 w = ((const float4*)W)[f];
        Ws[o * 66 + kq * 2]     = hh2{(_Float16)w.x, (_Float16)w.y};
        Ws[o * 66 + kq * 2 + 1] = hh2{(_Float16)w.z, (_Float16)w.w};
    }
#pragma unroll
    for (int r = 0; r < 8; ++r) {               // stage X tile (clamped tail)
        int f = t + 256 * r;
        int node = f >> 5, kq = f & 31;
        int gv = min(m0 + node, n - 1);
        float4 xv = ((const float4*)(x + (size_t)gv * IN_CH))[kq];
        Xs[node * 66 + kq * 2]     = hh2{(_Float16)xv.x, (_Float16)xv.y};
        Xs[node * 66 + kq * 2 + 1] = hh2{(_Float16)xv.z, (_Float16)xv.w};
    }
    __syncthreads();
    int tx = t & 15, ty = t >> 4;
    float acc[4][4];
#pragma unroll
    for (int i = 0; i < 4; ++i)
#pragma unroll
        for (int j = 0; j < 4; ++j) acc[i][j] = 0.f;

#pragma unroll 4
    for (int kq = 0; kq < 32; ++kq) {           // 4 k-values per step
        hh2 xa0[4], xa1[4], wb0[4], wb1[4];
#pragma unroll
        for (int i = 0; i < 4; ++i) {
            int base = (tx + 16 * i) * 66 + kq * 2;
            xa0[i] = Xs[base]; xa1[i] = Xs[base + 1];
        }
#pragma unroll
        for (int j = 0; j < 4; ++j) {
            int base = (ty * 4 + j) * 66 + kq * 2;
            wb0[j] = Ws[base]; wb1[j] = Ws[base + 1];
        }
#pragma unroll
        for (int i = 0; i < 4; ++i)
#pragma unroll
            for (int j = 0; j < 4; ++j) {
                float s = acc[i][j];
                s = __builtin_amdgcn_fdot2(xa0[i], wb0[j], s, false);
                s = __builtin_amdgcn_fdot2(xa1[i], wb1[j], s, false);
                acc[i][j] = s;
            }
    }
#pragma unroll
    for (int i = 0; i < 4; ++i) {
        int v = m0 + tx + 16 * i;
        if (v < n) {
            float dv = dis[v];
            union { __half2 h[2]; float2 f; } u;
            u.h[0] = __floats2half2_rn(dv * acc[i][0], dv * acc[i][1]);
            u.h[1] = __floats2half2_rn(dv * acc[i][2], dv * acc[i][3]);
            *(float2*)&z[(size_t)v * OUT_CH + ty * 4] = u.f;   // 8B aligned
        }
    }
}

// ---------------- propagation hop: wave per node, TWO 8-edge gather batches in flight ----------------
// t[v] = zin[v] + sum_{edges} zin[row]; rows are 64 halves = 128B.
// MODE 0: out(half) = dis^2 * t (next z);  MODE 1: out(float) = dis * t + bias.
template <int MODE>
__global__ void __launch_bounds__(256) hop_kernel(const __half* __restrict__ zin,
                                                  void* __restrict__ out,
                                                  const unsigned short* __restrict__ eidx,
                                                  const int* __restrict__ off,
                                                  const float* __restrict__ dis,
                                                  const float* __restrict__ bias, int n) {
    int v = (int)((blockIdx.x * 256 + threadIdx.x) >> 6);
    if (v >= n) return;
    int lane = threadIdx.x & 63;
    int grp = lane >> 3;       // edge slot in the octet
    int sub = lane & 7;        // 16B chunk of the 128B row
    int s = off[v], e = off[v + 1];
    float a0 = 0.f, a1 = 0.f, a2 = 0.f, a3 = 0.f;
    float a4 = 0.f, a5 = 0.f, a6 = 0.f, a7 = 0.f;
    if (grp == 0) {            // self-loop term (z already carries dis scaling)
        float4 raw = ((const float4*)(zin + (size_t)v * OUT_CH))[sub];
        const __half2* h2 = (const __half2*)&raw;
        float2 f0 = __half22float2(h2[0]), f1 = __half22float2(h2[1]);
        float2 f2 = __half22float2(h2[2]), f3 = __half22float2(h2[3]);
        a0 = f0.x; a1 = f0.y; a2 = f1.x; a3 = f1.y;
        a4 = f2.x; a5 = f2.y; a6 = f3.x; a7 = f3.y;
    }
    int i0 = s + grp, i1 = s + grp + 8;
    bool h0 = i0 < e, h1 = i1 < e;
    int r0 = h0 ? (int)eidx[i0] : 0;
    int r1 = h1 ? (int)eidx[i1] : 0;
    while (h0) {               // h1 implies h0
        int j0 = i0 + 16, j1 = i1 + 16;
        bool g0 = j0 < e, g1 = j1 < e;
        int q0 = g0 ? (int)eidx[j0] : 0;    // prefetch next descriptors
        int q1 = g1 ? (int)eidx[j1] : 0;
        float4 rawA = make_float4(0.f, 0.f, 0.f, 0.f);
        float4 rawB = make_float4(0.f, 0.f, 0.f, 0.f);
        if (h0) rawA = ((const float4*)(zin + (size_t)r0 * OUT_CH))[sub];
        if (h1) rawB = ((const float4*)(zin + (size_t)r1 * OUT_CH))[sub];
        {
            const __half2* hA = (const __half2*)&rawA;
            float2 f0 = __half22float2(hA[0]), f1 = __half22float2(hA[1]);
            float2 f2 = __half22float2(hA[2]), f3 = __half22float2(hA[3]);
            a0 += f0.x; a1 += f0.y; a2 += f1.x; a3 += f1.y;
            a4 += f2.x; a5 += f2.y; a6 += f3.x; a7 += f3.y;
        }
        {
            const __half2* hB = (const __half2*)&rawB;
            float2 f0 = __half22float2(hB[0]), f1 = __half22float2(hB[1]);
            float2 f2 = __half22float2(hB[2]), f3 = __half22float2(hB[3]);
            a0 += f0.x; a1 += f0.y; a2 += f1.x; a3 += f1.y;
            a4 += f2.x; a5 += f2.y; a6 += f3.x; a7 += f3.y;
        }
        i0 = j0; i1 = j1; r0 = q0; r1 = q1; h0 = g0; h1 = g1;
    }
    // reduce the 8 edge slots (lanes differing in bits 3..5)
#pragma unroll
    for (int m = 8; m <= 32; m <<= 1) {
        a0 += __shfl_xor(a0, m, 64); a1 += __shfl_xor(a1, m, 64);
        a2 += __shfl_xor(a2, m, 64); a3 += __shfl_xor(a3, m, 64);
        a4 += __shfl_xor(a4, m, 64); a5 += __shfl_xor(a5, m, 64);
        a6 += __shfl_xor(a6, m, 64); a7 += __shfl_xor(a7, m, 64);
    }
    if (grp == 0) {
        float dv = dis[v];
        if (MODE == 0) {
            float sc = dv * dv;
            union { __half2 h[4]; float4 f; } u;
            u.h[0] = __floats2half2_rn(sc * a0, sc * a1);
            u.h[1] = __floats2half2_rn(sc * a2, sc * a3);
            u.h[2] = __floats2half2_rn(sc * a4, sc * a5);
            u.h[3] = __floats2half2_rn(sc * a6, sc * a7);
            ((float4*)((__half*)out + (size_t)v * OUT_CH))[sub] = u.f;
        } else {
            const float4* bp = (const float4*)(bias + sub * 8);
            float4 b0 = bp[0], b1 = bp[1];
            float* op = (float*)out + (size_t)v * OUT_CH + sub * 8;
            *(float4*)op = make_float4(fmaf(dv, a0, b0.x), fmaf(dv, a1, b0.y),
                                       fmaf(dv, a2, b0.z), fmaf(dv, a3, b0.w));
            *(float4*)(op + 4) = make_float4(fmaf(dv, a4, b1.x), fmaf(dv, a5, b1.y),
                                             fmaf(dv, a6, b1.z), fmaf(dv, a7, b1.w));
        }
    }
}

extern "C" void kernel_launch(void* const* d_in, const int* in_sizes, int n_in,
                              void* d_out, int out_size, void* d_ws, size_t ws_size,
                              hipStream_t stream) {
    const float* x = (const float*)d_in[0];
    const int* ei = (const int*)d_in[1];
    const float* W = (const float*)d_in[2];
    const float* b = (const float*)d_in[3];
    int n = in_sizes[0] / IN_CH;   // 50000
    int E = in_sizes[1] / 2;       // 800000
    const int* row = ei;           // edge_index[0] = source
    const int* col = ei + E;       // edge_index[1] = target

    char* ws = (char*)d_ws;
    size_t o = 0;
    auto alloc = [&](size_t bytes) -> void* {
        void* p = ws + o;
        o += (bytes + 255) & ~(size_t)255;
        return p;
    };
    int nbkt = (n + 255) >> 8;      // 196
    int chunk = (E + NB - 1) / NB;  // 1563

    int*            blkcnt = (int*)alloc((size_t)NB * 256 * 4);
    int*            totals = (int*)alloc(256 * 4);
    unsigned int*   tmp    = (unsigned int*)alloc((size_t)E * 4);
    int*            off    = (int*)alloc((size_t)(n + 1) * 4);
    float*          dis    = (float*)alloc((size_t)n * 4);
    unsigned short* eidx   = (unsigned short*)alloc((size_t)E * 2);
    __half*         zA     = (__half*)alloc((size_t)n * OUT_CH * 2);
    __half*         zB     = (__half*)alloc((size_t)n * OUT_CH * 2);

    histo_kernel<<<NB, 512, 0, stream>>>(col, blkcnt, E, chunk);
    scanblk_kernel<<<nbkt, 256, 0, stream>>>(blkcnt, totals);
    bucket_scatter_kernel<<<NB, 512, 0, stream>>>(row, col, blkcnt, totals, tmp, E, chunk, nbkt);
    bucket_sort_kernel<<<nbkt, 512, 0, stream>>>(tmp, totals, off, dis, eidx, nbkt, E, n);
    gemm_kernel<<<(n + 63) / 64, 256, 0, stream>>>(x, W, dis, zA, n);
    int hopBlocks = (n + 3) / 4;   // wave per node
    hop_kernel<0><<<hopBlocks, 256, 0, stream>>>(zA, zB, eidx, off, dis, nullptr, n);
    hop_kernel<1><<<hopBlocks, 256, 0, stream>>>(zB, d_out, eidx, off, dis, b, n);
}